// Round 9
// baseline (88.278 us; speedup 1.0000x reference)
//
#include <hip/hip_runtime.h>
#include <math.h>

#define NB 2048
#define LL 200
#define DD 64
#define CC 9
#define HH 16
#define NW 4

// ---- d_ws layout (bytes) ----
// srow_g : int  [B*L]     @ 0          (1,638,400)
// z_g    : float[B*L]     @ 1,638,400  (1,638,400)
// cstart : int  [B*10]    @ 3,276,800  (81,920)
// gvec   : float[B*C*D]   @ 3,358,720  (4,718,592)  -- pre_g aliases this
//          (kB reads pre before kc overwrites with gvec)

// kA: per-user ballot sort + pre = b1 + W1u.u  -> srow_g, cstart_g, pre_g
__global__ __launch_bounds__(256) void din_ka(
    const int* __restrict__ user_inputs,
    const int* __restrict__ record_inputs,
    const int* __restrict__ item_cat,
    const float* __restrict__ user_emb,
    const float* __restrict__ W1,
    const float* __restrict__ b1,
    int* __restrict__ srow_g,
    int* __restrict__ cstart_g,
    float* __restrict__ pre_g)
{
  const int b = blockIdx.x;
  const int t = threadIdx.x;
  const int wave = t >> 6, lane = t & 63;

  __shared__ float u_s[DD];
  __shared__ int   wcnt[NW][CC];
  __shared__ int   cstart[CC + 1];

  int r = -1, c0 = -1;
  if (t < LL) {
    r = record_inputs[b * LL + t];
    if (r >= 0) c0 = item_cat[r];
  }
  if (t < DD) u_s[t] = user_emb[(size_t)user_inputs[b] * DD + t];

  int myrank = 0;
  #pragma unroll
  for (int c = 0; c < CC; ++c) {
    unsigned long long m = __ballot(c0 == c);
    if (lane == 0) wcnt[wave][c] = __popcll(m);
    if (c0 == c) myrank = __popcll(m & ((1ULL << lane) - 1ULL));
  }
  __syncthreads();

  if (t == 0) {
    int acc = 0;
    #pragma unroll
    for (int c = 0; c < CC; ++c) {
      cstart[c] = acc;
      acc += wcnt[0][c] + wcnt[1][c] + wcnt[2][c] + wcnt[3][c];
    }
    cstart[CC] = acc;
  }
  if (t < CC * HH) {   // pre = b1 + W1u . u  -> global
    int c = t / HH, j = t % HH;
    const float* wp = &W1[(size_t)(c * HH + j) * (2 * DD)];
    float acc = b1[c * HH + j];
    #pragma unroll 8
    for (int d = 0; d < DD; ++d) acc += wp[d] * u_s[d];
    pre_g[(size_t)(b * CC + c) * HH + j] = acc;
  }
  __syncthreads();

  if (c0 >= 0) {
    int off = cstart[c0];
    for (int w = 0; w < wave; ++w) off += wcnt[w][c0];
    srow_g[b * LL + off + myrank] = r;
  }
  if (t < CC + 1) cstart_g[b * 10 + t] = cstart[t];
}

// kB: full-occupancy score over all B*L slots. W1 e-half in LDS [ji][c].
__global__ __launch_bounds__(256) void din_kb(
    const float* __restrict__ item_emb,
    const float* __restrict__ W1,
    const float* __restrict__ W2,
    const float* __restrict__ b2,
    const int* __restrict__ srow_g,
    const int* __restrict__ cstart_g,
    const float* __restrict__ pre_g,
    float* __restrict__ z_g)
{
  const int t = threadIdx.x;

  __shared__ float4 w_lds[HH * 16 * CC];   // 36.9 KB
  __shared__ float  w2_s[CC * HH];
  __shared__ float  b2_s[CC];

  #pragma unroll
  for (int k = t; k < HH * 16 * CC; k += 256) {
    int c = k >> 8;
    int ji = k & 255;
    int j = ji >> 4, i = ji & 15;
    w_lds[ji * CC + c] = ((const float4*)W1)[(size_t)(c * HH + j) * 32 + 16 + i];
  }
  if (t < CC * HH) w2_s[t] = W2[t];
  if (t < CC) b2_s[t] = b2[t];
  __syncthreads();

  const int g = blockIdx.x * 256 + t;      // [0, B*LL)
  const int b = g / LL;
  const int pos = g - b * LL;
  const int cb = b * 10;
  const int nvalid = cstart_g[cb + CC];
  if (pos >= nvalid) return;

  int c = 0;
  #pragma unroll
  for (int q = 0; q < CC - 1; ++q) c += (pos >= cstart_g[cb + q + 1]) ? 1 : 0;

  const int row = srow_g[g];
  const float4* ep = (const float4*)&item_emb[(size_t)row * DD];

  float4 e[16];
  #pragma unroll
  for (int i = 0; i < 16; ++i) e[i] = ep[i];

  float acc[HH];
  const float4* pp = (const float4*)&pre_g[(size_t)(b * CC + c) * HH];
  #pragma unroll
  for (int jq = 0; jq < 4; ++jq) {
    float4 pv = pp[jq];
    acc[jq * 4 + 0] = pv.x; acc[jq * 4 + 1] = pv.y;
    acc[jq * 4 + 2] = pv.z; acc[jq * 4 + 3] = pv.w;
  }

  #pragma unroll
  for (int i = 0; i < 16; ++i) {
    float4 ev = e[i];
    #pragma unroll
    for (int j = 0; j < HH; ++j) {
      float4 wv = w_lds[(j * 16 + i) * CC + c];
      acc[j] += wv.x * ev.x + wv.y * ev.y + wv.z * ev.z + wv.w * ev.w;
    }
  }
  float s = b2_s[c];
  #pragma unroll
  for (int j = 0; j < HH; ++j) s += w2_s[c * HH + j] * fmaxf(acc[j], 0.f);
  z_g[g] = expf(s);
}

// kc: one wave per (b,c) pair, 8-deep ILP, barrier-free.
__global__ __launch_bounds__(256) void din_kc(
    const float* __restrict__ item_emb,
    const int* __restrict__ srow_g,
    const float* __restrict__ z_g,
    const int* __restrict__ cstart_g,
    float* __restrict__ gvec_g)
{
  const int pair = blockIdx.x * NW + (threadIdx.x >> 6);   // [0, B*C)
  const int lane = threadIdx.x & 63;
  const int b = pair / CC;
  const int c = pair - b * CC;
  const int base = b * LL;

  const int i0 = cstart_g[b * 10 + c];
  const int i1 = cstart_g[b * 10 + c + 1];

  float acc = 0.f;
  float zs = 0.f;

  for (int cb = i0; cb < i1; cb += 64) {
    const int nn = min(64, i1 - cb);
    const bool ok = (cb + lane < i1);
    int   rv = ok ? srow_g[base + cb + lane] : 0;
    float zv = ok ? z_g[base + cb + lane]    : 0.f;
    zs += zv;

    int k = 0;
    for (; k + 8 <= nn; k += 8) {
      int   r0 = __shfl(rv, k, 64),     r1 = __shfl(rv, k + 1, 64);
      int   r2 = __shfl(rv, k + 2, 64), r3 = __shfl(rv, k + 3, 64);
      int   r4 = __shfl(rv, k + 4, 64), r5 = __shfl(rv, k + 5, 64);
      int   r6 = __shfl(rv, k + 6, 64), r7 = __shfl(rv, k + 7, 64);
      float z0 = __shfl(zv, k, 64),     z1 = __shfl(zv, k + 1, 64);
      float z2 = __shfl(zv, k + 2, 64), z3 = __shfl(zv, k + 3, 64);
      float z4 = __shfl(zv, k + 4, 64), z5 = __shfl(zv, k + 5, 64);
      float z6 = __shfl(zv, k + 6, 64), z7 = __shfl(zv, k + 7, 64);
      float e0 = item_emb[(size_t)r0 * DD + lane];
      float e1 = item_emb[(size_t)r1 * DD + lane];
      float e2 = item_emb[(size_t)r2 * DD + lane];
      float e3 = item_emb[(size_t)r3 * DD + lane];
      float e4 = item_emb[(size_t)r4 * DD + lane];
      float e5 = item_emb[(size_t)r5 * DD + lane];
      float e6 = item_emb[(size_t)r6 * DD + lane];
      float e7 = item_emb[(size_t)r7 * DD + lane];
      acc += z0 * e0; acc += z1 * e1; acc += z2 * e2; acc += z3 * e3;
      acc += z4 * e4; acc += z5 * e5; acc += z6 * e6; acc += z7 * e7;
    }
    for (; k < nn; ++k) {
      int   rr = __shfl(rv, k, 64);
      float zz = __shfl(zv, k, 64);
      acc += zz * item_emb[(size_t)rr * DD + lane];
    }
  }

  #pragma unroll
  for (int off = 32; off > 0; off >>= 1) zs += __shfl_xor(zs, off, 64);
  const float inv = 1.f / fmaxf(zs, 1e-30f);

  gvec_g[(size_t)pair * DD + lane] = acc * inv;   // empty cat -> 0
}

// kd: per-user top-level attention + output
__global__ __launch_bounds__(256) void din_kd(
    const int* __restrict__ user_inputs,
    const int* __restrict__ item_inputs,
    const float* __restrict__ user_emb,
    const float* __restrict__ item_emb,
    const float* __restrict__ Wt1,
    const float* __restrict__ bt1,
    const float* __restrict__ Wt2,
    const float* __restrict__ bt2,
    const int* __restrict__ cstart_g,
    const float* __restrict__ gvec_g,
    float* __restrict__ out)
{
  const int b = blockIdx.x;
  const int t = threadIdx.x;

  __shared__ float u_s[DD];
  __shared__ float g_s[CC * DD];
  __shared__ float h2_s[CC][HH];
  __shared__ float w2_s[CC];
  __shared__ int   cnt_s[CC];

  if (t < DD) u_s[t] = user_emb[(size_t)user_inputs[b] * DD + t];
  for (int x = t; x < CC * DD; x += 256) g_s[x] = gvec_g[(size_t)b * CC * DD + x];
  if (t < CC) cnt_s[t] = cstart_g[b * 10 + t + 1] - cstart_g[b * 10 + t];
  __syncthreads();

  if (t < CC * HH) {
    int c = t / HH, j = t % HH;
    const float* wp = &Wt1[(size_t)j * (2 * DD)];
    float acc = bt1[j];
    #pragma unroll 8
    for (int d = 0; d < DD; ++d) acc += wp[d] * u_s[d];
    #pragma unroll 8
    for (int d = 0; d < DD; ++d) acc += wp[DD + d] * g_s[c * DD + d];
    h2_s[c][j] = fmaxf(acc, 0.f);
  }
  __syncthreads();

  if (t == 0) {
    float s2[CC];
    float m = -INFINITY;
    #pragma unroll
    for (int c = 0; c < CC; ++c) {
      float acc = bt2[0];
      #pragma unroll
      for (int j = 0; j < HH; ++j) acc += Wt2[j] * h2_s[c][j];
      s2[c] = acc;
      if (cnt_s[c] > 0) m = fmaxf(m, acc);
    }
    if (m == -INFINITY) m = 0.f;
    float sum = 0.f;
    float z2[CC];
    #pragma unroll
    for (int c = 0; c < CC; ++c) {
      z2[c] = (cnt_s[c] > 0) ? expf(s2[c] - m) : 0.f;
      sum += z2[c];
    }
    float inv = 1.f / fmaxf(sum, 1e-30f);
    #pragma unroll
    for (int c = 0; c < CC; ++c) w2_s[c] = z2[c] * inv;
  }
  __syncthreads();

  if (t < DD) {
    float hy = 0.f;
    #pragma unroll
    for (int c = 0; c < CC; ++c) hy += w2_s[c] * g_s[c * DD + t];
    float ti = item_emb[(size_t)item_inputs[b] * DD + t];
    float prod = hy * ti;
    #pragma unroll
    for (int off = 32; off > 0; off >>= 1)
      prod += __shfl_down(prod, off, 64);
    if (t == 0) out[b] = prod;
  }
}

extern "C" void kernel_launch(void* const* d_in, const int* in_sizes, int n_in,
                              void* d_out, int out_size, void* d_ws, size_t ws_size,
                              hipStream_t stream) {
  const int*   user_inputs   = (const int*)d_in[0];
  const int*   record_inputs = (const int*)d_in[1];
  const int*   item_inputs   = (const int*)d_in[2];
  const int*   item_cat      = (const int*)d_in[3];
  const float* user_emb      = (const float*)d_in[4];
  const float* item_emb      = (const float*)d_in[5];
  const float* W1            = (const float*)d_in[6];
  const float* b1            = (const float*)d_in[7];
  const float* W2            = (const float*)d_in[8];
  const float* b2            = (const float*)d_in[9];
  const float* Wt1           = (const float*)d_in[10];
  const float* bt1           = (const float*)d_in[11];
  const float* Wt2           = (const float*)d_in[12];
  const float* bt2           = (const float*)d_in[13];
  float* out = (float*)d_out;

  char* ws = (char*)d_ws;
  int*   srow_g   = (int*)(ws);                 // B*L ints
  float* z_g      = (float*)(ws + 1638400);     // B*L floats
  int*   cstart_g = (int*)(ws + 3276800);       // B*10 ints
  float* gvec_g   = (float*)(ws + 3358720);     // B*C*D floats
  float* pre_g    = (float*)(ws + 3358720);     // aliases gvec (read before kc)

  din_ka<<<NB, 256, 0, stream>>>(user_inputs, record_inputs, item_cat,
                                 user_emb, W1, b1, srow_g, cstart_g, pre_g);
  din_kb<<<(NB * LL) / 256, 256, 0, stream>>>(item_emb, W1, W2, b2,
                                              srow_g, cstart_g, pre_g, z_g);
  din_kc<<<(NB * CC) / NW, 256, 0, stream>>>(item_emb, srow_g, z_g, cstart_g, gvec_g);
  din_kd<<<NB, 256, 0, stream>>>(user_inputs, item_inputs, user_emb, item_emb,
                                 Wt1, bt1, Wt2, bt2, cstart_g, gvec_g, out);
}

// Round 10
// 82.351 us; speedup vs baseline: 1.0720x; 1.0720x over previous
//
#include <hip/hip_runtime.h>
#include <math.h>

#define NB 2048
#define LL 200
#define PADL 256   // padded per-user slot stride (max needed 200+9*3=227)
#define DD 64
#define CC 9
#define HH 16
#define NW 4

// ---- d_ws layout (bytes) ----
// srow_g : int  [B*PADL]  @ 0          (2,097,152)
// z_g    : float[B*PADL]  @ 2,097,152  (2,097,152)
// cstart : int  [B*20]    @ 4,194,304  (163,840)   [0..9]=padded starts, [10..18]=counts
// gvec   : float[B*C*D]   @ 4,358,144  (4,718,592) -- pre_g aliases (read before kc writes)
// total 9,076,736 B

// kA: per-user ballot sort (4-aligned padded groups) + pre = b1 + W1u.u
__global__ __launch_bounds__(256) void din_ka(
    const int* __restrict__ user_inputs,
    const int* __restrict__ record_inputs,
    const int* __restrict__ item_cat,
    const float* __restrict__ user_emb,
    const float* __restrict__ W1,
    const float* __restrict__ b1,
    int* __restrict__ srow_g,
    int* __restrict__ cstart_g,
    float* __restrict__ pre_g)
{
  const int b = blockIdx.x;
  const int t = threadIdx.x;
  const int wave = t >> 6, lane = t & 63;

  __shared__ float u_s[DD];
  __shared__ int   wcnt[NW][CC];
  __shared__ int   cstart[CC + 1];
  __shared__ int   ccnt[CC];

  int r = -1, c0 = -1;
  if (t < LL) {
    r = record_inputs[b * LL + t];
    if (r >= 0) c0 = item_cat[r];
  }
  if (t < DD) u_s[t] = user_emb[(size_t)user_inputs[b] * DD + t];

  srow_g[b * PADL + t] = 0;   // default rows for pad slots (row 0 is valid memory)

  int myrank = 0;
  #pragma unroll
  for (int c = 0; c < CC; ++c) {
    unsigned long long m = __ballot(c0 == c);
    if (lane == 0) wcnt[wave][c] = __popcll(m);
    if (c0 == c) myrank = __popcll(m & ((1ULL << lane) - 1ULL));
  }
  __syncthreads();

  if (t == 0) {
    int acc = 0;
    #pragma unroll
    for (int c = 0; c < CC; ++c) {
      cstart[c] = acc;
      int cn = wcnt[0][c] + wcnt[1][c] + wcnt[2][c] + wcnt[3][c];
      ccnt[c] = cn;
      acc = (acc + cn + 3) & ~3;   // 4-aligned next group
    }
    cstart[CC] = acc;
  }
  if (t < CC * HH) {   // pre = b1 + W1u . u  -> global
    int c = t / HH, j = t % HH;
    const float* wp = &W1[(size_t)(c * HH + j) * (2 * DD)];
    float acc = b1[c * HH + j];
    #pragma unroll 8
    for (int d = 0; d < DD; ++d) acc += wp[d] * u_s[d];
    pre_g[(size_t)(b * CC + c) * HH + j] = acc;
  }
  __syncthreads();

  if (c0 >= 0) {
    int off = cstart[c0];
    for (int w = 0; w < wave; ++w) off += wcnt[w][c0];
    srow_g[b * PADL + off + myrank] = r;
  }
  if (t < CC + 1) cstart_g[b * 20 + t] = cstart[t];
  else if (t < 2 * CC + 1) cstart_g[b * 20 + 10 + (t - CC - 1)] = ccnt[t - CC - 1];
}

// kB: 4 same-category items per thread; W1 e-half in LDS [ji][c], read once per 16 FMAs.
__global__ __launch_bounds__(256) void din_kb(
    const float* __restrict__ item_emb,
    const float* __restrict__ W1,
    const float* __restrict__ W2,
    const float* __restrict__ b2,
    const int* __restrict__ srow_g,
    const int* __restrict__ cstart_g,
    const float* __restrict__ pre_g,
    float* __restrict__ z_g)
{
  const int t = threadIdx.x;

  __shared__ float4 w_lds[HH * 16 * CC];   // 36.9 KB
  __shared__ float  w2_s[CC * HH];
  __shared__ float  b2_s[CC];

  #pragma unroll
  for (int k = t; k < HH * 16 * CC; k += 256) {
    int c = k >> 8;
    int ji = k & 255;
    int j = ji >> 4, i = ji & 15;
    w_lds[ji * CC + c] = ((const float4*)W1)[(size_t)(c * HH + j) * 32 + 16 + i];
  }
  if (t < CC * HH) w2_s[t] = W2[t];
  if (t < CC) b2_s[t] = b2[t];
  __syncthreads();

  const int g = blockIdx.x * 256 + t;      // [0, B*64): one thread = 4 slots
  const int b = g >> 6;
  const int q4 = (g & 63) * 4;             // base slot (4-aligned)
  const int* cs = &cstart_g[b * 20];
  if (q4 >= cs[CC]) return;                // beyond padded total

  int c = 0;
  #pragma unroll
  for (int q = 0; q < CC - 1; ++q) c += (q4 >= cs[q + 1]) ? 1 : 0;

  const int base = b * PADL + q4;
  const int r0 = srow_g[base + 0], r1 = srow_g[base + 1];
  const int r2 = srow_g[base + 2], r3 = srow_g[base + 3];
  const float4* e0 = (const float4*)&item_emb[(size_t)r0 * DD];
  const float4* e1 = (const float4*)&item_emb[(size_t)r1 * DD];
  const float4* e2 = (const float4*)&item_emb[(size_t)r2 * DD];
  const float4* e3 = (const float4*)&item_emb[(size_t)r3 * DD];

  float acc0[HH], acc1[HH], acc2[HH], acc3[HH];
  {
    const float4* pp = (const float4*)&pre_g[(size_t)(b * CC + c) * HH];
    #pragma unroll
    for (int jq = 0; jq < 4; ++jq) {
      float4 pv = pp[jq];
      acc0[jq*4+0] = pv.x; acc0[jq*4+1] = pv.y; acc0[jq*4+2] = pv.z; acc0[jq*4+3] = pv.w;
      acc1[jq*4+0] = pv.x; acc1[jq*4+1] = pv.y; acc1[jq*4+2] = pv.z; acc1[jq*4+3] = pv.w;
      acc2[jq*4+0] = pv.x; acc2[jq*4+1] = pv.y; acc2[jq*4+2] = pv.z; acc2[jq*4+3] = pv.w;
      acc3[jq*4+0] = pv.x; acc3[jq*4+1] = pv.y; acc3[jq*4+2] = pv.z; acc3[jq*4+3] = pv.w;
    }
  }

  #pragma unroll
  for (int i = 0; i < 16; ++i) {
    float4 a0 = e0[i], a1 = e1[i], a2 = e2[i], a3 = e3[i];
    #pragma unroll
    for (int j = 0; j < HH; ++j) {
      float4 wv = w_lds[(j * 16 + i) * CC + c];
      acc0[j] += wv.x * a0.x + wv.y * a0.y + wv.z * a0.z + wv.w * a0.w;
      acc1[j] += wv.x * a1.x + wv.y * a1.y + wv.z * a1.z + wv.w * a1.w;
      acc2[j] += wv.x * a2.x + wv.y * a2.y + wv.z * a2.z + wv.w * a2.w;
      acc3[j] += wv.x * a3.x + wv.y * a3.y + wv.z * a3.z + wv.w * a3.w;
    }
  }

  float s0 = b2_s[c], s1 = s0, s2 = s0, s3 = s0;
  #pragma unroll
  for (int j = 0; j < HH; ++j) {
    float w2v = w2_s[c * HH + j];
    s0 += w2v * fmaxf(acc0[j], 0.f);
    s1 += w2v * fmaxf(acc1[j], 0.f);
    s2 += w2v * fmaxf(acc2[j], 0.f);
    s3 += w2v * fmaxf(acc3[j], 0.f);
  }
  *(float4*)&z_g[base] = make_float4(expf(s0), expf(s1), expf(s2), expf(s3));
}

// kc: one wave per (b,c) pair, 8-deep ILP, barrier-free.
__global__ __launch_bounds__(256) void din_kc(
    const float* __restrict__ item_emb,
    const int* __restrict__ srow_g,
    const float* __restrict__ z_g,
    const int* __restrict__ cstart_g,
    float* __restrict__ gvec_g)
{
  const int pair = blockIdx.x * NW + (threadIdx.x >> 6);   // [0, B*C)
  const int lane = threadIdx.x & 63;
  const int b = pair / CC;
  const int c = pair - b * CC;
  const int base = b * PADL;

  const int i0 = cstart_g[b * 20 + c];
  const int i1 = i0 + cstart_g[b * 20 + 10 + c];

  float acc = 0.f;
  float zs = 0.f;

  for (int cb = i0; cb < i1; cb += 64) {
    const int nn = min(64, i1 - cb);
    const bool ok = (cb + lane < i1);
    int   rv = ok ? srow_g[base + cb + lane] : 0;
    float zv = ok ? z_g[base + cb + lane]    : 0.f;
    zs += zv;

    int k = 0;
    for (; k + 8 <= nn; k += 8) {
      int   r0 = __shfl(rv, k, 64),     r1 = __shfl(rv, k + 1, 64);
      int   r2 = __shfl(rv, k + 2, 64), r3 = __shfl(rv, k + 3, 64);
      int   r4 = __shfl(rv, k + 4, 64), r5 = __shfl(rv, k + 5, 64);
      int   r6 = __shfl(rv, k + 6, 64), r7 = __shfl(rv, k + 7, 64);
      float z0 = __shfl(zv, k, 64),     z1 = __shfl(zv, k + 1, 64);
      float z2 = __shfl(zv, k + 2, 64), z3 = __shfl(zv, k + 3, 64);
      float z4 = __shfl(zv, k + 4, 64), z5 = __shfl(zv, k + 5, 64);
      float z6 = __shfl(zv, k + 6, 64), z7 = __shfl(zv, k + 7, 64);
      float e0 = item_emb[(size_t)r0 * DD + lane];
      float e1 = item_emb[(size_t)r1 * DD + lane];
      float e2 = item_emb[(size_t)r2 * DD + lane];
      float e3 = item_emb[(size_t)r3 * DD + lane];
      float e4 = item_emb[(size_t)r4 * DD + lane];
      float e5 = item_emb[(size_t)r5 * DD + lane];
      float e6 = item_emb[(size_t)r6 * DD + lane];
      float e7 = item_emb[(size_t)r7 * DD + lane];
      acc += z0 * e0; acc += z1 * e1; acc += z2 * e2; acc += z3 * e3;
      acc += z4 * e4; acc += z5 * e5; acc += z6 * e6; acc += z7 * e7;
    }
    for (; k < nn; ++k) {
      int   rr = __shfl(rv, k, 64);
      float zz = __shfl(zv, k, 64);
      acc += zz * item_emb[(size_t)rr * DD + lane];
    }
  }

  #pragma unroll
  for (int off = 32; off > 0; off >>= 1) zs += __shfl_xor(zs, off, 64);
  const float inv = 1.f / fmaxf(zs, 1e-30f);

  gvec_g[(size_t)pair * DD + lane] = acc * inv;   // empty cat -> 0
}

// kd: per-user top-level attention + output
__global__ __launch_bounds__(256) void din_kd(
    const int* __restrict__ user_inputs,
    const int* __restrict__ item_inputs,
    const float* __restrict__ user_emb,
    const float* __restrict__ item_emb,
    const float* __restrict__ Wt1,
    const float* __restrict__ bt1,
    const float* __restrict__ Wt2,
    const float* __restrict__ bt2,
    const int* __restrict__ cstart_g,
    const float* __restrict__ gvec_g,
    float* __restrict__ out)
{
  const int b = blockIdx.x;
  const int t = threadIdx.x;

  __shared__ float u_s[DD];
  __shared__ float g_s[CC * DD];
  __shared__ float h2_s[CC][HH];
  __shared__ float w2_s[CC];
  __shared__ int   cnt_s[CC];

  if (t < DD) u_s[t] = user_emb[(size_t)user_inputs[b] * DD + t];
  for (int x = t; x < CC * DD; x += 256) g_s[x] = gvec_g[(size_t)b * CC * DD + x];
  if (t < CC) cnt_s[t] = cstart_g[b * 20 + 10 + t];
  __syncthreads();

  if (t < CC * HH) {
    int c = t / HH, j = t % HH;
    const float* wp = &Wt1[(size_t)j * (2 * DD)];
    float acc = bt1[j];
    #pragma unroll 8
    for (int d = 0; d < DD; ++d) acc += wp[d] * u_s[d];
    #pragma unroll 8
    for (int d = 0; d < DD; ++d) acc += wp[DD + d] * g_s[c * DD + d];
    h2_s[c][j] = fmaxf(acc, 0.f);
  }
  __syncthreads();

  if (t == 0) {
    float s2[CC];
    float m = -INFINITY;
    #pragma unroll
    for (int c = 0; c < CC; ++c) {
      float acc = bt2[0];
      #pragma unroll
      for (int j = 0; j < HH; ++j) acc += Wt2[j] * h2_s[c][j];
      s2[c] = acc;
      if (cnt_s[c] > 0) m = fmaxf(m, acc);
    }
    if (m == -INFINITY) m = 0.f;
    float sum = 0.f;
    float z2[CC];
    #pragma unroll
    for (int c = 0; c < CC; ++c) {
      z2[c] = (cnt_s[c] > 0) ? expf(s2[c] - m) : 0.f;
      sum += z2[c];
    }
    float inv = 1.f / fmaxf(sum, 1e-30f);
    #pragma unroll
    for (int c = 0; c < CC; ++c) w2_s[c] = z2[c] * inv;
  }
  __syncthreads();

  if (t < DD) {
    float hy = 0.f;
    #pragma unroll
    for (int c = 0; c < CC; ++c) hy += w2_s[c] * g_s[c * DD + t];
    float ti = item_emb[(size_t)item_inputs[b] * DD + t];
    float prod = hy * ti;
    #pragma unroll
    for (int off = 32; off > 0; off >>= 1)
      prod += __shfl_down(prod, off, 64);
    if (t == 0) out[b] = prod;
  }
}

extern "C" void kernel_launch(void* const* d_in, const int* in_sizes, int n_in,
                              void* d_out, int out_size, void* d_ws, size_t ws_size,
                              hipStream_t stream) {
  const int*   user_inputs   = (const int*)d_in[0];
  const int*   record_inputs = (const int*)d_in[1];
  const int*   item_inputs   = (const int*)d_in[2];
  const int*   item_cat      = (const int*)d_in[3];
  const float* user_emb      = (const float*)d_in[4];
  const float* item_emb      = (const float*)d_in[5];
  const float* W1            = (const float*)d_in[6];
  const float* b1            = (const float*)d_in[7];
  const float* W2            = (const float*)d_in[8];
  const float* b2            = (const float*)d_in[9];
  const float* Wt1           = (const float*)d_in[10];
  const float* bt1           = (const float*)d_in[11];
  const float* Wt2           = (const float*)d_in[12];
  const float* bt2           = (const float*)d_in[13];
  float* out = (float*)d_out;

  char* ws = (char*)d_ws;
  int*   srow_g   = (int*)(ws);                 // B*PADL ints
  float* z_g      = (float*)(ws + 2097152);     // B*PADL floats
  int*   cstart_g = (int*)(ws + 4194304);       // B*20 ints
  float* gvec_g   = (float*)(ws + 4358144);     // B*C*D floats
  float* pre_g    = (float*)(ws + 4358144);     // aliases gvec (read before kc)

  din_ka<<<NB, 256, 0, stream>>>(user_inputs, record_inputs, item_cat,
                                 user_emb, W1, b1, srow_g, cstart_g, pre_g);
  din_kb<<<(NB * 64) / 256, 256, 0, stream>>>(item_emb, W1, W2, b2,
                                              srow_g, cstart_g, pre_g, z_g);
  din_kc<<<(NB * CC) / NW, 256, 0, stream>>>(item_emb, srow_g, z_g, cstart_g, gvec_g);
  din_kd<<<NB, 256, 0, stream>>>(user_inputs, item_inputs, user_emb, item_emb,
                                 Wt1, bt1, Wt2, bt2, cstart_g, gvec_g, out);
}